// Round 1
// baseline (87.854 us; speedup 1.0000x reference)
//
#include <hip/hip_runtime.h>

#define NT   24
#define CIN  9
#define NF   32
#define KM   16
#define HID  128
#define NCLS 10
#define SEQ_LEN (NT*CIN)   // 216
#define PADJ 12            // column pitch (floats), 16B-aligned float4 reads
#define GSEQ 4             // sequences per block

// One thread = one (sequence, filter) DTW. 65536 threads total, fully
// independent: no shfl, no skew fill/drain, no exec-mask divergence.
// Whole filter lives in registers (144 VGPR, -2 prescaled), column state
// rowD[16] in registers; per column: 3 broadcast ds_read_b128 + 160 fma
// (independent across rows -> hides the serial min-chain).
// 1 wave/SIMD by construction (1024 waves) -> __launch_bounds__(128,1)
// gives the allocator the full 512-VGPR budget; ~220 expected, no spill.
//
// Numerics replicate the previous passing kernel exactly:
//   cost = (arow[r] + bj) then 9 fma in channel order; fmin nesting over
//   the same operand set (min is exact -> order-free); col-0 cumsum in row
//   order; MLP partial-accumulator split (a0+a1)+(a2+a3); same softmax.
__global__ __launch_bounds__(128, 1) void dtwnet_fused(
    const float* __restrict__ x,
    const float* __restrict__ kern,
    const float* __restrict__ W1, const float* __restrict__ b1,
    const float* __restrict__ W2, const float* __restrict__ b2,
    const float* __restrict__ Wl, const float* __restrict__ bl,
    float* __restrict__ out)
{
  __shared__ float seq_lds[GSEQ][NT*PADJ];
  __shared__ float bcol[GSEQ][NT];
  __shared__ float feat[GSEQ][NF];
  __shared__ float h1[GSEQ][HID];
  __shared__ float h2[GSEQ][HID];
  __shared__ float logit_lds[GSEQ][NCLS];

  const int tid = threadIdx.x;
  const int bid = blockIdx.x;
  const int g   = tid >> 5;    // sequence within block (0..3)
  const int f   = tid & 31;    // filter (0..31)

  // ---- whole filter (16x9) into registers
  float kf[KM*CIN];
  {
    const float4* kp = (const float4*)(kern + f*(KM*CIN));
    #pragma unroll
    for (int i = 0; i < (KM*CIN)/4; ++i) {
      float4 t = kp[i];
      kf[4*i+0]=t.x; kf[4*i+1]=t.y; kf[4*i+2]=t.z; kf[4*i+3]=t.w;
    }
  }

  // ---- stage 4 sequences (4*216 floats) into LDS, padded pitch 12
  #pragma unroll
  for (int it = 0; it < 7; ++it) {
    int d = tid + it*128;
    if (d < GSEQ*SEQ_LEN) {
      int gg  = d / SEQ_LEN;
      int rem = d - gg*SEQ_LEN;
      int jj  = rem / CIN;
      int cc  = rem - jj*CIN;
      seq_lds[gg][jj*PADJ + cc] = x[(bid*GSEQ + gg)*SEQ_LEN + rem];
    }
  }

  // ---- a[r] = ||k_r||^2, then prescale kf by -2 (overlaps staging)
  float arow[KM];
  #pragma unroll
  for (int r = 0; r < KM; ++r) {
    float a = 0.f;
    #pragma unroll
    for (int c = 0; c < CIN; ++c) a = fmaf(kf[r*CIN+c], kf[r*CIN+c], a);
    arow[r] = a;
  }
  #pragma unroll
  for (int q = 0; q < KM*CIN; ++q) kf[q] *= -2.f;

  __syncthreads();

  // ---- column norms ||x_j||^2 (96 values), exact same expression as before
  if (tid < GSEQ*NT) {
    int gg = tid / NT;
    int jj = tid - gg*NT;
    const float4* sp = (const float4*)(&seq_lds[gg][jj*PADJ]);
    float4 q0 = sp[0], q1 = sp[1], q2 = sp[2];
    float b = q0.x*q0.x + q0.y*q0.y + q0.z*q0.z + q0.w*q0.w
            + q1.x*q1.x + q1.y*q1.y + q1.z*q1.z + q1.w*q1.w
            + q2.x*q2.x;
    bcol[gg][jj] = b;
  }
  __syncthreads();

  // ---- DTW: full 16-row column sweep, all state in registers
  const float* scol = &seq_lds[g][0];
  float rowD[KM];
  {
    // column 0: up-only cumulative chain (row order, same as before)
    const float4* sp = (const float4*)scol;
    float4 q0 = sp[0], q1 = sp[1], q2 = sp[2];
    float sv[CIN] = {q0.x,q0.y,q0.z,q0.w,q1.x,q1.y,q1.z,q1.w,q2.x};
    float bj = bcol[g][0];
    float acc = 0.f;
    #pragma unroll
    for (int r = 0; r < KM; ++r) {
      float cc = arow[r] + bj;
      #pragma unroll
      for (int c = 0; c < CIN; ++c) cc = fmaf(kf[r*CIN+c], sv[c], cc);
      acc += cc;
      rowD[r] = acc;
    }
  }
  #pragma unroll 2
  for (int j = 1; j < NT; ++j) {
    const float4* sp = (const float4*)(scol + j*PADJ);
    float4 q0 = sp[0], q1 = sp[1], q2 = sp[2];
    float sv[CIN] = {q0.x,q0.y,q0.z,q0.w,q1.x,q1.y,q1.z,q1.w,q2.x};
    float bj = bcol[g][j];
    float nD[KM];
    {
      // row 0: left-only
      float cc = arow[0] + bj;
      #pragma unroll
      for (int c = 0; c < CIN; ++c) cc = fmaf(kf[c], sv[c], cc);
      nD[0] = cc + rowD[0];
    }
    #pragma unroll
    for (int r = 1; r < KM; ++r) {
      float cc = arow[r] + bj;
      #pragma unroll
      for (int c = 0; c < CIN; ++c) cc = fmaf(kf[r*CIN+c], sv[c], cc);
      // left = rowD[r] (col j-1), up = nD[r-1] (col j), diag = rowD[r-1] (col j-1)
      nD[r] = cc + fminf(rowD[r], fminf(nD[r-1], rowD[r-1]));
    }
    #pragma unroll
    for (int r = 0; r < KM; ++r) rowD[r] = nD[r];
  }

  feat[g][f] = rowD[KM-1];
  __syncthreads();

  // ---- MLP layer 1: each thread computes unit `tid` for all 4 seqs
  //      (weight loads amortized x4). Single sequential accumulator per
  //      seq, k ascending — same fma order as the previous kernel.
  {
    float b1v = b1[tid];
    float a0 = b1v, a1 = b1v, a2 = b1v, a3 = b1v;
    const float4* f0 = (const float4*)&feat[0][0];
    const float4* f1 = (const float4*)&feat[1][0];
    const float4* f2 = (const float4*)&feat[2][0];
    const float4* f3 = (const float4*)&feat[3][0];
    #pragma unroll
    for (int k4 = 0; k4 < NF/4; ++k4) {
      float4 v0 = f0[k4], v1 = f1[k4], v2 = f2[k4], v3 = f3[k4];
      float w0 = W1[(4*k4+0)*HID + tid];
      float w1 = W1[(4*k4+1)*HID + tid];
      float w2 = W1[(4*k4+2)*HID + tid];
      float w3 = W1[(4*k4+3)*HID + tid];
      a0 = fmaf(v0.x,w0,a0); a0 = fmaf(v0.y,w1,a0); a0 = fmaf(v0.z,w2,a0); a0 = fmaf(v0.w,w3,a0);
      a1 = fmaf(v1.x,w0,a1); a1 = fmaf(v1.y,w1,a1); a1 = fmaf(v1.z,w2,a1); a1 = fmaf(v1.w,w3,a1);
      a2 = fmaf(v2.x,w0,a2); a2 = fmaf(v2.y,w1,a2); a2 = fmaf(v2.z,w2,a2); a2 = fmaf(v2.w,w3,a2);
      a3 = fmaf(v3.x,w0,a3); a3 = fmaf(v3.y,w1,a3); a3 = fmaf(v3.z,w2,a3); a3 = fmaf(v3.w,w3,a3);
    }
    h1[0][tid] = fmaxf(a0, 0.f);
    h1[1][tid] = fmaxf(a1, 0.f);
    h1[2][tid] = fmaxf(a2, 0.f);
    h1[3][tid] = fmaxf(a3, 0.f);
  }
  __syncthreads();

  // ---- layer 2: 4 partial accumulators per seq, (a0+a1)+(a2+a3) — exact
  //      replication of the previous kernel's summation association.
  {
    float b2v = b2[tid];
    float p00=b2v, p01=0.f, p02=0.f, p03=0.f;
    float p10=b2v, p11=0.f, p12=0.f, p13=0.f;
    float p20=b2v, p21=0.f, p22=0.f, p23=0.f;
    float p30=b2v, p31=0.f, p32=0.f, p33=0.f;
    const float4* q0p = (const float4*)&h1[0][0];
    const float4* q1p = (const float4*)&h1[1][0];
    const float4* q2p = (const float4*)&h1[2][0];
    const float4* q3p = (const float4*)&h1[3][0];
    #pragma unroll
    for (int k4 = 0; k4 < HID/4; ++k4) {
      float4 v0 = q0p[k4], v1 = q1p[k4], v2 = q2p[k4], v3 = q3p[k4];
      float w0 = W2[(4*k4+0)*HID + tid];
      float w1 = W2[(4*k4+1)*HID + tid];
      float w2 = W2[(4*k4+2)*HID + tid];
      float w3 = W2[(4*k4+3)*HID + tid];
      p00 = fmaf(v0.x,w0,p00); p01 = fmaf(v0.y,w1,p01); p02 = fmaf(v0.z,w2,p02); p03 = fmaf(v0.w,w3,p03);
      p10 = fmaf(v1.x,w0,p10); p11 = fmaf(v1.y,w1,p11); p12 = fmaf(v1.z,w2,p12); p13 = fmaf(v1.w,w3,p13);
      p20 = fmaf(v2.x,w0,p20); p21 = fmaf(v2.y,w1,p21); p22 = fmaf(v2.z,w2,p22); p23 = fmaf(v2.w,w3,p23);
      p30 = fmaf(v3.x,w0,p30); p31 = fmaf(v3.y,w1,p31); p32 = fmaf(v3.z,w2,p32); p33 = fmaf(v3.w,w3,p33);
    }
    h2[0][tid] = fmaxf((p00+p01)+(p02+p03), 0.f);
    h2[1][tid] = fmaxf((p10+p11)+(p12+p13), 0.f);
    h2[2][tid] = fmaxf((p20+p21)+(p22+p23), 0.f);
    h2[3][tid] = fmaxf((p30+p31)+(p32+p33), 0.f);
  }
  __syncthreads();

  // ---- logits: 40 lanes, one (seq, class) each; same partial split
  if (tid < GSEQ*NCLS) {
    int gg = tid / NCLS;
    int c  = tid - gg*NCLS;
    const float4* hh = (const float4*)&h2[gg][0];
    float a0 = bl[c], a1 = 0.f, a2 = 0.f, a3 = 0.f;
    #pragma unroll
    for (int k4 = 0; k4 < HID/4; ++k4) {
      float4 h4 = hh[k4];
      a0 = fmaf(h4.x, Wl[(4*k4+0)*NCLS + c], a0);
      a1 = fmaf(h4.y, Wl[(4*k4+1)*NCLS + c], a1);
      a2 = fmaf(h4.z, Wl[(4*k4+2)*NCLS + c], a2);
      a3 = fmaf(h4.w, Wl[(4*k4+3)*NCLS + c], a3);
    }
    logit_lds[gg][c] = (a0 + a1) + (a2 + a3);
  }
  __syncthreads();

  // ---- softmax: 4 lanes, one sequence each (same serial order as before)
  if (tid < GSEQ) {
    float mx = logit_lds[tid][0];
    #pragma unroll
    for (int jj = 1; jj < NCLS; ++jj) mx = fmaxf(mx, logit_lds[tid][jj]);
    float e[NCLS]; float sum = 0.f;
    #pragma unroll
    for (int jj = 0; jj < NCLS; ++jj) { e[jj] = __expf(logit_lds[tid][jj] - mx); sum += e[jj]; }
    float inv = 1.f / sum;
    float* op = out + (bid*GSEQ + tid)*NCLS;
    #pragma unroll
    for (int jj = 0; jj < NCLS; ++jj) op[jj] = e[jj] * inv;
  }
}

extern "C" void kernel_launch(void* const* d_in, const int* in_sizes, int n_in,
                              void* d_out, int out_size, void* d_ws, size_t ws_size,
                              hipStream_t stream) {
  const float* x    = (const float*)d_in[0];
  const float* kern = (const float*)d_in[1];
  const float* W1   = (const float*)d_in[2];
  const float* b1   = (const float*)d_in[3];
  const float* W2   = (const float*)d_in[4];
  const float* b2   = (const float*)d_in[5];
  const float* Wl   = (const float*)d_in[6];
  const float* bl   = (const float*)d_in[7];
  float* out = (float*)d_out;

  dtwnet_fused<<<512, 128, 0, stream>>>(x, kern, W1, b1, W2, b2, Wl, bl, out);
}

// Round 2
// 83.592 us; speedup vs baseline: 1.0510x; 1.0510x over previous
//
#include <hip/hip_runtime.h>

#define NT   24
#define CIN  9
#define NF   32
#define KM   16
#define HID  128
#define NCLS 10
#define SEQ_LEN (NT*CIN)   // 216
#define PADJ 12            // seq LDS row pitch (floats), 16B-aligned columns
#define NSTRIP 4           // 4 strips of 4 rows; pipelined via shfl

// D[m-1,n-1] (forward DTW) == backtracked path-cost sum (telescoping; only fp
// summation order differs). Cost uses the quadratic expansion:
//   ||k-x||^2 = ||k||^2 + ||x||^2 - 2 k.x
// with kf pre-scaled by -2 and the accumulator seeded with a[r]+b[j]:
// per cell = 1 add + 9 fma (vs 9 sub + 9 fma direct). D is min-plus in the
// costs, so near-tie path flips do not perturb D — expansion noise (~1e-5)
// passes straight through to the features.
//
// Thread layout: block = 128 threads = 2 waves, 1 sequence per block.
// lane = strip*16 + f_lo ; filter f = wave*16 + f_lo.
// Strip s computes rows [4s,4s+4), skewed: step t works column j = t-s.
// Boundary D flows strip s -> s+1 via __shfl_up(.,16).
//
// NOTE (session finding, R1): measured dur_us ≈ 80 µs of harness 256-MiB
// poison fills (2 × ~40 µs, visible as the only big dispatches in rocprof)
// + ~3.4 µs kernel. Kernel-side is at ~85-100% of the fp32 VALU issue
// roofline (310M lane-fma ≈ 3.9 µs @ 157.3 TF; no fp32 MFMA on CDNA4).
// The 4-wave/SIMD TLP here beats the 1-wave/SIMD ILP design (R1: +5 µs).
__global__ __launch_bounds__(128, 4) void dtwnet_fused(
    const float* __restrict__ x,
    const float* __restrict__ kern,
    const float* __restrict__ W1, const float* __restrict__ b1,
    const float* __restrict__ W2, const float* __restrict__ b2,
    const float* __restrict__ Wl, const float* __restrict__ bl,
    float* __restrict__ out)
{
  __shared__ float seq_lds[NT*PADJ];
  __shared__ float bcol[NT];          // ||x_j||^2 per column
  __shared__ float feat_lds[NF];
  __shared__ float h1_lds[HID];
  __shared__ float h2_lds[HID];
  __shared__ float logit_lds[NCLS];

  const int tid  = threadIdx.x;
  const int bid  = blockIdx.x;
  const int wave = tid >> 6;
  const int lane = tid & 63;
  const int s    = lane >> 4;       // strip 0..3
  const int f_lo = lane & 15;
  const int f    = wave*16 + f_lo;  // filter 0..31

  // filter strip (4 rows x 9 ch) from global (L2-hot), issued pre-barrier
  float kf[4*CIN];
  {
    const float4* kp = (const float4*)(kern + f*(KM*CIN) + s*(4*CIN));
    float4 t0 = kp[0], t1 = kp[1], t2 = kp[2], t3 = kp[3], t4 = kp[4],
           t5 = kp[5], t6 = kp[6], t7 = kp[7], t8 = kp[8];
    kf[0]=t0.x; kf[1]=t0.y; kf[2]=t0.z; kf[3]=t0.w;
    kf[4]=t1.x; kf[5]=t1.y; kf[6]=t1.z; kf[7]=t1.w;
    kf[8]=t2.x; kf[9]=t2.y; kf[10]=t2.z; kf[11]=t2.w;
    kf[12]=t3.x; kf[13]=t3.y; kf[14]=t3.z; kf[15]=t3.w;
    kf[16]=t4.x; kf[17]=t4.y; kf[18]=t4.z; kf[19]=t4.w;
    kf[20]=t5.x; kf[21]=t5.y; kf[22]=t5.z; kf[23]=t5.w;
    kf[24]=t6.x; kf[25]=t6.y; kf[26]=t6.z; kf[27]=t6.w;
    kf[28]=t7.x; kf[29]=t7.y; kf[30]=t7.z; kf[31]=t7.w;
    kf[32]=t8.x; kf[33]=t8.y; kf[34]=t8.z; kf[35]=t8.w;
  }

  // stage this block's sequence (216 floats), padded to 12/timestep
  for (int d = tid; d < SEQ_LEN; d += 128) {
    int jj = d / CIN, cc = d - jj*CIN;
    seq_lds[jj*PADJ + cc] = x[bid*SEQ_LEN + d];
  }
  __syncthreads();

  // column norms ||x_j||^2 (24 values, one thread each)
  if (tid < NT) {
    const float4* sp = (const float4*)(seq_lds + tid*PADJ);
    float4 q0 = sp[0], q1 = sp[1], q2 = sp[2];
    float b = q0.x*q0.x + q0.y*q0.y + q0.z*q0.z + q0.w*q0.w
            + q1.x*q1.x + q1.y*q1.y + q1.z*q1.z + q1.w*q1.w
            + q2.x*q2.x;
    bcol[tid] = b;
  }

  // a[r] = ||k_r||^2, then pre-scale kf by -2
  float arow[4];
  #pragma unroll
  for (int r = 0; r < 4; ++r) {
    float a = 0.f;
    #pragma unroll
    for (int c = 0; c < CIN; ++c) a = fmaf(kf[r*CIN+c], kf[r*CIN+c], a);
    arow[r] = a;
  }
  #pragma unroll
  for (int q = 0; q < 4*CIN; ++q) kf[q] *= -2.f;
  __syncthreads();

  float rowD[4];
  float bndUp = 0.f, bndDg = 0.f;

  #pragma unroll 1
  for (int t = 0; t < NT + NSTRIP - 1; ++t) {
    int j = t - s;                        // this strip's column
    bool active = (j >= 0) && (j < NT);
    float nb = 0.f;
    if (active) {
      const float4* sp = (const float4*)(seq_lds + j*PADJ);
      float4 q0 = sp[0], q1 = sp[1], q2 = sp[2];
      float bj = bcol[j];
      float sv[CIN] = {q0.x,q0.y,q0.z,q0.w,q1.x,q1.y,q1.z,q1.w,q2.x};
      float cost[4];
      #pragma unroll
      for (int r = 0; r < 4; ++r) {
        float cc = arow[r] + bj;
        #pragma unroll
        for (int c = 0; c < CIN; ++c) cc = fmaf(kf[r*CIN+c], sv[c], cc);
        cost[r] = cc;
      }
      if (j == 0) {
        // column 0: up-only chain (row 0 starts at 0)
        float acc = (s == 0) ? 0.f : bndUp;
        #pragma unroll
        for (int r = 0; r < 4; ++r) { acc += cost[r]; rowD[r] = acc; }
      } else {
        float up, diag;
        float left = rowD[0];
        float D0;
        if (s == 0) {
          D0 = cost[0] + left;                       // global row 0: left-only
        } else {
          D0 = cost[0] + fminf(bndDg, fminf(bndUp, left));
        }
        diag = left;
        rowD[0] = D0; up = D0;
        #pragma unroll
        for (int r = 1; r < 4; ++r) {
          float lD = rowD[r];
          float D2 = cost[r] + fminf(diag, fminf(up, lD));
          diag = lD;
          rowD[r] = D2; up = D2;
        }
      }
      nb = rowD[3];
    }
    // wave-wide boundary hand-off to the next strip
    float rD = __shfl_up(nb, 16u);
    bndDg = bndUp;
    bndUp = rD;
  }

  if (s == 3) feat_lds[f] = rowD[3];
  __syncthreads();

  // --- MLP: 32 -> 128 relu -> 128 relu -> 10 softmax (1 seq / block) ---
  {
    float acc = b1[tid];
    #pragma unroll
    for (int k = 0; k < NF; ++k) acc = fmaf(feat_lds[k], W1[k*HID + tid], acc);
    h1_lds[tid] = fmaxf(acc, 0.f);
  }
  __syncthreads();
  {
    const float4* hh = (const float4*)h1_lds;
    float a0 = b2[tid], a1 = 0.f, a2 = 0.f, a3 = 0.f;
    #pragma unroll
    for (int k = 0; k < HID/4; ++k) {
      float4 h4 = hh[k];
      a0 = fmaf(h4.x, W2[(4*k+0)*HID + tid], a0);
      a1 = fmaf(h4.y, W2[(4*k+1)*HID + tid], a1);
      a2 = fmaf(h4.z, W2[(4*k+2)*HID + tid], a2);
      a3 = fmaf(h4.w, W2[(4*k+3)*HID + tid], a3);
    }
    h2_lds[tid] = fmaxf((a0 + a1) + (a2 + a3), 0.f);
  }
  __syncthreads();
  if (tid < NCLS) {
    const float4* hh = (const float4*)h2_lds;
    float a0 = bl[tid], a1 = 0.f, a2 = 0.f, a3 = 0.f;
    #pragma unroll
    for (int k = 0; k < HID/4; ++k) {
      float4 h4 = hh[k];
      a0 = fmaf(h4.x, Wl[(4*k+0)*NCLS + tid], a0);
      a1 = fmaf(h4.y, Wl[(4*k+1)*NCLS + tid], a1);
      a2 = fmaf(h4.z, Wl[(4*k+2)*NCLS + tid], a2);
      a3 = fmaf(h4.w, Wl[(4*k+3)*NCLS + tid], a3);
    }
    logit_lds[tid] = (a0 + a1) + (a2 + a3);
  }
  __syncthreads();
  if (tid == 0) {
    float mx = logit_lds[0];
    #pragma unroll
    for (int j = 1; j < NCLS; ++j) mx = fmaxf(mx, logit_lds[j]);
    float e[NCLS]; float sum = 0.f;
    #pragma unroll
    for (int j = 0; j < NCLS; ++j) { e[j] = __expf(logit_lds[j] - mx); sum += e[j]; }
    float inv = 1.f / sum;
    float* op = out + bid*NCLS;
    #pragma unroll
    for (int j = 0; j < NCLS; ++j) op[j] = e[j] * inv;
  }
}

extern "C" void kernel_launch(void* const* d_in, const int* in_sizes, int n_in,
                              void* d_out, int out_size, void* d_ws, size_t ws_size,
                              hipStream_t stream) {
  const float* x    = (const float*)d_in[0];
  const float* kern = (const float*)d_in[1];
  const float* W1   = (const float*)d_in[2];
  const float* b1   = (const float*)d_in[3];
  const float* W2   = (const float*)d_in[4];
  const float* b2   = (const float*)d_in[5];
  const float* Wl   = (const float*)d_in[6];
  const float* bl   = (const float*)d_in[7];
  float* out = (float*)d_out;

  dtwnet_fused<<<2048, 128, 0, stream>>>(x, kern, W1, b1, W2, b2, Wl, bl, out);
}